// Round 7
// baseline (127.828 us; speedup 1.0000x reference)
//
#include <hip/hip_runtime.h>

// Problem: A=8, B=16, N=M=1024, K=64. u:(A,B,N,K) f32, v:(A,B,M,K) f32.
// out0 = u * (dot(u_row, v_sum) > 0), out1 = v * (dot(v_row, u_sum) > 0)
//
// 512 blocks x 512 threads, block = (batch, tensor, half). Each block:
//   - register-holds 512 rows of its own tensor (16 float4/thread),
//   - streams the OTHER tensor's full batch from L3 to build the one colsum
//     it needs (u rows are masked by v_sum only, v rows by u_sum only),
//   - masks + NT-stores its own rows from registers.
// ~2 blocks/CU co-resident -> one block's writes overlap another's reads
// (round-6 structure had 1 block/CU: reads then writes fully serialized).

#define NBATCH 128        // A*B
#define NROW   1024       // N == M
#define KDIM   64
#define ELEMS_PER_TENSOR (128ull * 1024ull * 64ull)  // 8388608

typedef float floatx4 __attribute__((ext_vector_type(4)));  // for nontemporal builtin

__global__ __launch_bounds__(512)
void fused_split_kernel(const float* __restrict__ u,
                        const float* __restrict__ v,
                        float* __restrict__ out) {
    const int bid    = blockIdx.x;       // 0..511
    const int batch  = bid >> 2;         // 0..127
    const int tensor = (bid >> 1) & 1;   // 0 = u rows, 1 = v rows
    const int half   = bid & 1;          // own rows: [half*512, half*512+512)
    const int tid    = threadIdx.x;      // 0..511
    const int k4     = tid & 15;         // float4 column group
    const int rg     = tid >> 4;         // 0..31 row group
    const int wave   = tid >> 6;         // 0..7

    const float* own_p = tensor ? v : u;
    const float* oth_p = tensor ? u : v;
    const float4* ob = (const float4*)(own_p + (size_t)batch * NROW * KDIM);
    const float4* xb = (const float4*)(oth_p + (size_t)batch * NROW * KDIM);

    // ---- Phase A1: own 512 rows -> registers (16 float4/thread) ----
    const int r_own0 = half * 512 + rg;
    float4 mine[16];
    #pragma unroll
    for (int i = 0; i < 16; ++i) {
        // wave covers 4 consecutive rows x 256B each: coalesced 1KB/instr
        mine[i] = ob[(size_t)(r_own0 + 32 * i) * 16 + k4];
    }

    // ---- Phase A2: stream other tensor's full batch, accumulate colsum ----
    float4 so = make_float4(0.f, 0.f, 0.f, 0.f);
    #pragma unroll
    for (int j = 0; j < 32; ++j) {
        float4 a = xb[(size_t)(rg + 32 * j) * 16 + k4];
        so.x += a.x; so.y += a.y; so.z += a.z; so.w += a.w;
    }

    // reduce the 4 row-groups within each wave (lanes sharing k4: +-16, +-32)
    so.x += __shfl_xor(so.x, 16); so.y += __shfl_xor(so.y, 16);
    so.z += __shfl_xor(so.z, 16); so.w += __shfl_xor(so.w, 16);
    so.x += __shfl_xor(so.x, 32); so.y += __shfl_xor(so.y, 32);
    so.z += __shfl_xor(so.z, 32); so.w += __shfl_xor(so.w, 32);

    __shared__ float4 red[8][16];       // [wave][k4]
    __shared__ float4 fsum[16];         // final colsum of the other tensor
    if ((tid & 63) < 16) red[wave][k4] = so;
    __syncthreads();

    if (tid < 16) {
        float4 t = make_float4(0.f, 0.f, 0.f, 0.f);
        #pragma unroll
        for (int i = 0; i < 8; ++i) {
            float4 a = red[i][tid];
            t.x += a.x; t.y += a.y; t.z += a.z; t.w += a.w;
        }
        fsum[tid] = t;
    }
    __syncthreads();

    const float4 cs = fsum[k4];

    // ---- Phase B: mask own rows from registers, streaming stores ----
    float* dst = out + (size_t)tensor * ELEMS_PER_TENSOR
                     + (size_t)batch * NROW * KDIM;
    #pragma unroll
    for (int i = 0; i < 16; ++i) {
        size_t io = (size_t)(r_own0 + 32 * i) * 16 + k4;
        float p = mine[i].x * cs.x + mine[i].y * cs.y
                + mine[i].z * cs.z + mine[i].w * cs.w;
        p += __shfl_xor(p, 1);
        p += __shfl_xor(p, 2);
        p += __shfl_xor(p, 4);
        p += __shfl_xor(p, 8);
        float m = (p > 0.f) ? 1.f : 0.f;
        floatx4 o = { mine[i].x * m, mine[i].y * m, mine[i].z * m, mine[i].w * m };
        __builtin_nontemporal_store(o, (floatx4*)(dst + io * 4));
    }
}

extern "C" void kernel_launch(void* const* d_in, const int* in_sizes, int n_in,
                              void* d_out, int out_size, void* d_ws, size_t ws_size,
                              hipStream_t stream) {
    const float* u = (const float*)d_in[0];
    const float* v = (const float*)d_in[1];
    float* out = (float*)d_out;

    fused_split_kernel<<<dim3(512), dim3(512), 0, stream>>>(u, v, out);
}

// Round 8
// 127.406 us; speedup vs baseline: 1.0033x; 1.0033x over previous
//
#include <hip/hip_runtime.h>

// Problem: A=8, B=16, N=M=1024, K=64. u:(A,B,N,K) f32, v:(A,B,M,K) f32.
// out0 = u * (dot(u_row, v_sum) > 0), out1 = v * (dot(v_row, u_sum) > 0)
//
// Single kernel, exactly-once reads, per-batch flag sync (no grid sync, no
// cooperative launch). Block = (batch, tensor, half):
//   1. load own 512 rows -> registers (16 float4/thread)
//   2. reduce own-tensor partial colsum, publish via agent-scope atomics
//   3. release-store MAGIC flag; spin-wait (acquire) on the OTHER tensor's
//      2 flags (u rows need only v_sum and vice versa)
//   4. fold partials, mask own rows from registers, NT-store
// Deadlock-safe: publish-before-wait; 2 blocks/CU (VGPR<=128) => all 512
// blocks co-resident; flags distinguished from 0xAA poison by MAGIC value.
//
// ws layout: int flags[128][2][2] at byte 0; float part[128][2][2][64] at 4096.

#define NBATCH 128
#define NROW   1024
#define KDIM   64
#define ELEMS_PER_TENSOR (128ull * 1024ull * 64ull)
#define MAGIC  0x13572468

typedef float floatx4 __attribute__((ext_vector_type(4)));

__global__ __launch_bounds__(512, 4)
void fused_flag_kernel(const float* __restrict__ u,
                       const float* __restrict__ v,
                       float* __restrict__ out,
                       int* __restrict__ flags,
                       float* __restrict__ part) {
    const int bid    = blockIdx.x;       // 0..511
    const int batch  = bid >> 2;         // 0..127
    const int tensor = (bid >> 1) & 1;   // 0 = u rows, 1 = v rows
    const int half   = bid & 1;          // own rows: [half*512, half*512+512)
    const int tid    = threadIdx.x;      // 0..511
    const int k4     = tid & 15;         // float4 column group
    const int rg     = tid >> 4;         // 0..31 row group
    const int wave   = tid >> 6;         // 0..7

    const float* own_p = tensor ? v : u;
    const float4* ob = (const float4*)(own_p + (size_t)batch * NROW * KDIM);

    // ---- 1. own 512 rows -> registers; accumulate own colsum partial ----
    const int r0 = half * 512 + rg;
    float4 mine[16];
    float4 s = make_float4(0.f, 0.f, 0.f, 0.f);
    #pragma unroll
    for (int i = 0; i < 16; ++i) {
        mine[i] = ob[(size_t)(r0 + 32 * i) * 16 + k4];   // 1KB/wave, coalesced
        s.x += mine[i].x; s.y += mine[i].y; s.z += mine[i].z; s.w += mine[i].w;
    }

    // reduce across the 4 row-groups sharing k4 within each wave (lane ^16, ^32)
    s.x += __shfl_xor(s.x, 16); s.y += __shfl_xor(s.y, 16);
    s.z += __shfl_xor(s.z, 16); s.w += __shfl_xor(s.w, 16);
    s.x += __shfl_xor(s.x, 32); s.y += __shfl_xor(s.y, 32);
    s.z += __shfl_xor(s.z, 32); s.w += __shfl_xor(s.w, 32);

    __shared__ float4 red[8][16];        // [wave][k4]
    if ((tid & 63) < 16) red[wave][k4] = s;
    __syncthreads();

    // ---- 2. fold 8 waves; publish partial (agent-scope, reaches coherent pt)
    float* mypart = part + (((size_t)batch * 2 + tensor) * 2 + half) * KDIM;
    if (tid < 16) {
        float4 t = make_float4(0.f, 0.f, 0.f, 0.f);
        #pragma unroll
        for (int i = 0; i < 8; ++i) {
            float4 a = red[i][tid];
            t.x += a.x; t.y += a.y; t.z += a.z; t.w += a.w;
        }
        __hip_atomic_store(mypart + tid * 4 + 0, t.x, __ATOMIC_RELAXED, __HIP_MEMORY_SCOPE_AGENT);
        __hip_atomic_store(mypart + tid * 4 + 1, t.y, __ATOMIC_RELAXED, __HIP_MEMORY_SCOPE_AGENT);
        __hip_atomic_store(mypart + tid * 4 + 2, t.z, __ATOMIC_RELAXED, __HIP_MEMORY_SCOPE_AGENT);
        __hip_atomic_store(mypart + tid * 4 + 3, t.w, __ATOMIC_RELAXED, __HIP_MEMORY_SCOPE_AGENT);
    }
    __syncthreads();   // drains vmem: partials are at the coherent point

    // ---- 3. release own flag, then acquire-spin on the other tensor's two
    const int other = 1 - tensor;
    if (tid == 0) {
        int* myflag = flags + ((batch * 2 + tensor) * 2 + half);
        __hip_atomic_store(myflag, MAGIC, __ATOMIC_RELEASE, __HIP_MEMORY_SCOPE_AGENT);
    }
    if (tid < 2) {
        int* oflag = flags + ((batch * 2 + other) * 2 + tid);
        while (__hip_atomic_load(oflag, __ATOMIC_ACQUIRE, __HIP_MEMORY_SCOPE_AGENT) != MAGIC) {
            __builtin_amdgcn_s_sleep(1);
        }
    }
    __syncthreads();

    // ---- fold the other tensor's 2 partials -> colsum in LDS ----
    __shared__ float csum[KDIM];
    const float* op = part + (((size_t)batch * 2 + other) * 2 + 0) * KDIM;
    if (tid < KDIM) {
        float a = __hip_atomic_load(op + tid,        __ATOMIC_RELAXED, __HIP_MEMORY_SCOPE_AGENT);
        float b = __hip_atomic_load(op + KDIM + tid, __ATOMIC_RELAXED, __HIP_MEMORY_SCOPE_AGENT);
        csum[tid] = a + b;
    }
    __syncthreads();
    const float4 cs = *(const float4*)(csum + k4 * 4);   // 2-way bank alias: free

    // ---- 4. mask own rows from registers, streaming stores ----
    float* dst = out + (size_t)tensor * ELEMS_PER_TENSOR
                     + (size_t)batch * NROW * KDIM;
    #pragma unroll
    for (int i = 0; i < 16; ++i) {
        size_t io = (size_t)(r0 + 32 * i) * 16 + k4;
        float p = mine[i].x * cs.x + mine[i].y * cs.y
                + mine[i].z * cs.z + mine[i].w * cs.w;
        p += __shfl_xor(p, 1);
        p += __shfl_xor(p, 2);
        p += __shfl_xor(p, 4);
        p += __shfl_xor(p, 8);
        float m = (p > 0.f) ? 1.f : 0.f;
        floatx4 o = { mine[i].x * m, mine[i].y * m, mine[i].z * m, mine[i].w * m };
        __builtin_nontemporal_store(o, (floatx4*)(dst + io * 4));
    }
}

extern "C" void kernel_launch(void* const* d_in, const int* in_sizes, int n_in,
                              void* d_out, int out_size, void* d_ws, size_t ws_size,
                              hipStream_t stream) {
    const float* u = (const float*)d_in[0];
    const float* v = (const float*)d_in[1];
    float* out = (float*)d_out;
    int*   flags = (int*)d_ws;                         // 2 KB (poisoned != MAGIC)
    float* part  = (float*)((char*)d_ws + 4096);       // 128 KB

    fused_flag_kernel<<<dim3(512), dim3(512), 0, stream>>>(u, v, out, flags, part);
}